// Round 4
// baseline (280.716 us; speedup 1.0000x reference)
//
#include <hip/hip_runtime.h>

// FindInstancePeaks: fused conv backbone + global peak finding.
// crops (128,192,192,1) f32 -> conv1 3x3 s2 SAME (1->32) + relu
//                          -> conv2 3x3 s1 SAME (32->17) = cms (128,96,96,17)
// -> per (b,n): argmax over 96x96, quarter-pixel sign refine, *2, NaN<0.2.
//
// R12: R11 confirmed fp32 packed FMA is HALF-RATE on CDNA4 (157.3 TF spec
// == scalar v_fmac issue rate exactly; two different conv2 codings gave
// identical 117us VALU-busy) and the "s"-constraint asm caused spills
// (WRITE_SIZE 3264->7872 KB). Revert to scalar fmaf. Remaining loss is
// 31% barrier-convoy idle: all 6 blocks/CU hit identical-length phases.
// Restructure each group to software-pipeline across the two barriers:
//   [A] read hr(cl0) -> 459 FMAs(cl0) -> read hr(cl1) -> [B]
//       -> conv1(g+1) overlapped with 459 FMAs(cl1)
// All conv2 LDS reads precede barrier B (hazard-safe: s_h overwrite only
// after B); conv1 latency chains hide under cl1's FMA block. Only 15 hr
// floats live across B -> peak live ~81 VGPR <= 84 cap of (256,6).
// Accumulation order unchanged (g asc; cl0 k0..8 then cl1 k0..8) ->
// bit-exact output preserved.

#define NCH 17
#define C1 32
#define TW 24           // tile width
#define TH 32           // tile height
#define HT_W 26         // h cols needed (TW+2)
#define HT_H 34         // h rows needed (TH+2)
#define HSTR 28         // s_h col stride
#define IN_W 53         // input patch cols: 2*HT_W+1
#define IN_H 69         // input patch rows: 2*HT_H+1
#define NG 16           // groups of 2 conv1 channels
#define NHPX (HT_H * HT_W)   // 884 h-pixels per block

__device__ __forceinline__ unsigned long long pack_key(float v, unsigned flat) {
    unsigned ub = __float_as_uint(v);
    ub = (ub & 0x80000000u) ? ~ub : (ub | 0x80000000u);   // monotone float->uint
    return ((unsigned long long)ub << 32) | (unsigned)(~flat); // ~flat: ties -> lowest idx
}

// conv1 + relu for group g (channels 2g, 2g+1) into planar s_h.
// Weights/bias are uniform -> s_loads (SGPRs). Validity via *{0,1}.
__device__ __forceinline__ void conv1_group(
    const float* __restrict__ W1g, const float* __restrict__ b1g,
    const float* s_in, float* s_h, int g, int t, int ty0, int tx0) {
    const int c0 = 2 * g, c1 = 2 * g + 1;
    const float b10 = b1g[c0], b11 = b1g[c1];
    float w10[9], w11[9];
#pragma unroll
    for (int q = 0; q < 9; ++q) {
        w10[q] = W1g[q * C1 + c0];
        w11[q] = W1g[q * C1 + c1];
    }
#pragma unroll
    for (int i = 0; i < 4; ++i) {
        int p = t + i * 256;
        if (i < 3 || p < NHPX) {
            int r = p / HT_W, cc = p - r * HT_W;
            int hy = ty0 - 1 + r, hx = tx0 - 1 + cc;
            float vf = (hy >= 0 && hy < 96 && hx >= 0 && hx < 96) ? 1.f : 0.f;
            const float* ip = s_in + 2 * r * IN_W + 2 * cc;
            float a0 = b10, a1 = b11;
#pragma unroll
            for (int qy = 0; qy < 3; ++qy)
#pragma unroll
                for (int qx = 0; qx < 3; ++qx) {
                    float x = ip[qy * IN_W + qx];
                    a0 = fmaf(x, w10[qy * 3 + qx], a0);
                    a1 = fmaf(x, w11[qy * 3 + qx], a1);
                }
            a0 = fmaxf(a0, 0.f) * vf;
            a1 = fmaxf(a1, 0.f) * vf;
            s_h[r * HSTR + cc] = a0;
            s_h[HT_H * HSTR + r * HSTR + cc] = a1;
        }
    }
}

__global__ __launch_bounds__(256, 6) void conv_peaks_kernel(
    const float* __restrict__ crops, const float* __restrict__ W1g,
    const float* __restrict__ b1g, const float* __restrict__ W2g,
    const float* __restrict__ b2g, unsigned long long* __restrict__ peaks) {
    __shared__ __align__(16) float s_in[IN_H * IN_W];        // 14628 B
    __shared__ __align__(16) float s_h[2 * HT_H * HSTR];     // 7616 B (planar)

    const int t = threadIdx.x;
    const int b = blockIdx.y;
    const int ty0 = (blockIdx.x >> 2) * TH;   // 0,32,64
    const int tx0 = (blockIdx.x & 3) * TW;    // 0,24,48,72
    const int iy0 = 2 * ty0 - 2;
    const int ix0 = 2 * tx0 - 2;
    const float* cb = crops + b * 192 * 192;

    // --- stage input patch (zero-padded at image borders) ---
    for (int p = t; p < IN_H * IN_W; p += 256) {
        int r = p / IN_W, cc = p - r * IN_W;
        int iy = iy0 + r, ix = ix0 + cc;
        float v = 0.f;
        if (iy >= 0 && ix >= 0 && iy < 192 && ix < 192) v = cb[iy * 192 + ix];
        s_in[p] = v;
    }
    __syncthreads();
    conv1_group(W1g, b1g, s_in, s_h, 0, t, ty0, tx0);   // prologue

    // thread -> 3 contiguous pixels: row ly, cols lx0..lx0+2
    const int ly = t >> 3;            // 0..31
    const int lx0 = (t & 7) * 3;      // 0,3,...,21
    const float* hpbase = s_h + ly * HSTR + lx0;
    float acc[NCH][3];
#pragma unroll
    for (int n = 0; n < NCH; ++n)
#pragma unroll
        for (int p = 0; p < 3; ++p) acc[n][p] = 0.f;

#pragma unroll 1
    for (int g = 0; g < NG; ++g) {
        __syncthreads();   // A: conv1(g) writes visible

        // ---- cl = 0: read 15 h floats, then 459 register FMAs ----
        {
            float hr[3][5];
#pragma unroll
            for (int ky = 0; ky < 3; ++ky)
#pragma unroll
                for (int j = 0; j < 5; ++j) hr[ky][j] = hpbase[ky * HSTR + j];
            const int c = 2 * g;
#pragma unroll
            for (int k = 0; k < 9; ++k) {
                const int ky = k / 3, kx = k - ky * 3;
                const float* wb = W2g + (k * C1 + c) * NCH;  // uniform -> s_load
                float w[NCH];
#pragma unroll
                for (int n = 0; n < NCH; ++n) w[n] = wb[n];
#pragma unroll
                for (int p = 0; p < 3; ++p) {
                    const float h = hr[ky][kx + p];
#pragma unroll
                    for (int n = 0; n < NCH; ++n)
                        acc[n][p] = fmaf(h, w[n], acc[n][p]);
                }
            }
        }

        // ---- cl = 1: reads must precede barrier B ----
        float hr1[3][5];
#pragma unroll
        for (int ky = 0; ky < 3; ++ky)
#pragma unroll
            for (int j = 0; j < 5; ++j)
                hr1[ky][j] = hpbase[HT_H * HSTR + ky * HSTR + j];

        __syncthreads();   // B: all reads of s_h(g) done -> safe to overwrite

        if (g < NG - 1)
            conv1_group(W1g, b1g, s_in, s_h, g + 1, t, ty0, tx0);

        {
            const int c = 2 * g + 1;
#pragma unroll
            for (int k = 0; k < 9; ++k) {
                const int ky = k / 3, kx = k - ky * 3;
                const float* wb = W2g + (k * C1 + c) * NCH;  // uniform -> s_load
                float w[NCH];
#pragma unroll
                for (int n = 0; n < NCH; ++n) w[n] = wb[n];
#pragma unroll
                for (int p = 0; p < 3; ++p) {
                    const float h = hr1[ky][kx + p];
#pragma unroll
                    for (int n = 0; n < NCH; ++n)
                        acc[n][p] = fmaf(h, w[n], acc[n][p]);
                }
            }
        }
    }

    // --- per-channel argmax: in-thread max over 3 px, then wave reduce ---
    const int yg = ty0 + ly, xg = tx0 + lx0;
    const int lane = t & 63;
#pragma unroll
    for (int n = 0; n < NCH; ++n) {
        const float bb = b2g[n];
        unsigned long long pk = pack_key(acc[n][0] + bb, (unsigned)(yg * 96 + xg));
#pragma unroll
        for (int p = 1; p < 3; ++p) {
            unsigned long long o = pack_key(acc[n][p] + bb, (unsigned)(yg * 96 + xg + p));
            if (o > pk) pk = o;
        }
#pragma unroll
        for (int off = 32; off; off >>= 1) {
            unsigned long long o = __shfl_down(pk, off, 64);
            if (o > pk) pk = o;
        }
        if (lane == 0) atomicMax(&peaks[b * NCH + n], pk);
    }
}

// One 64-lane wave per (b,n): decode peak, recompute 4 clipped neighbor cms
// values (b2 cancels in the sign differences), emit (x,y,val).
__global__ __launch_bounds__(64) void refine_kernel(
    const float* __restrict__ crops, const float* __restrict__ W1g,
    const float* __restrict__ b1g, const float* __restrict__ W2g,
    const unsigned long long* __restrict__ peaks, float* __restrict__ out) {
    const int bn = blockIdx.x;          // 0..128*17-1
    const int b = bn / NCH, n = bn % NCH;
    const int lane = threadIdx.x;

    unsigned long long pk = peaks[bn];
    unsigned key = (unsigned)(pk >> 32);
    unsigned fbits = (key & 0x80000000u) ? (key ^ 0x80000000u) : ~key;
    float val = __uint_as_float(fbits);
    int flat = (int)(~(unsigned)(pk & 0xffffffffu));
    int yi = flat / 96, xi = flat - yi * 96;

    // neighbor j: 0:(yi,xi+1) 1:(yi,xi-1) 2:(yi+1,xi) 3:(yi-1,xi), clipped
    const int j = lane >> 4;
    int yy = yi + ((j == 2) ? 1 : 0) - ((j == 3) ? 1 : 0);
    int xx = xi + ((j == 0) ? 1 : 0) - ((j == 1) ? 1 : 0);
    yy = min(max(yy, 0), 95);
    xx = min(max(xx, 0), 95);

    // hoist 7x7 crops patch: rows 2yy-2..2yy+4, cols 2xx-2..2xx+4
    const float* cb = crops + b * 192 * 192;
    float pat[7][7];
#pragma unroll
    for (int r = 0; r < 7; ++r) {
        int iy = 2 * yy - 2 + r;
#pragma unroll
        for (int s = 0; s < 7; ++s) {
            int ix = 2 * xx - 2 + s;
            pat[r][s] = (iy >= 0 && iy < 192 && ix >= 0 && ix < 192)
                            ? cb[iy * 192 + ix] : 0.f;
        }
    }

    float part = 0.f;
#pragma unroll
    for (int ci = 0; ci < 2; ++ci) {
        const int c = (lane & 15) + ci * 16;
        const float bias = b1g[c];
        float w1[9];
#pragma unroll
        for (int q = 0; q < 9; ++q) w1[q] = W1g[q * C1 + c];
#pragma unroll
        for (int dy = 0; dy < 3; ++dy) {
#pragma unroll
            for (int dx = 0; dx < 3; ++dx) {
                int hy = yy - 1 + dy, hx = xx - 1 + dx;
                if (hy >= 0 && hy < 96 && hx >= 0 && hx < 96) {
                    float a = bias;
#pragma unroll
                    for (int qy = 0; qy < 3; ++qy)
#pragma unroll
                        for (int qx = 0; qx < 3; ++qx)
                            a = fmaf(pat[2 * dy + qy][2 * dx + qx],
                                     w1[qy * 3 + qx], a);
                    float hval = fmaxf(a, 0.f);
                    part = fmaf(hval, W2g[((dy * 3 + dx) * C1 + c) * NCH + n], part);
                }
            }
        }
    }
    // sum the 16 lanes of each neighbor group
    for (int off = 8; off; off >>= 1) part += __shfl_down(part, off, 16);
    float g0 = __shfl(part, 0, 64);
    float g1 = __shfl(part, 16, 64);
    float g2 = __shfl(part, 32, 64);
    float g3 = __shfl(part, 48, 64);

    if (lane == 0) {
        float d0 = g0 - g1, d1 = g2 - g3;
        float sx = (d0 > 0.f) ? 1.f : ((d0 < 0.f) ? -1.f : 0.f);
        float sy = (d1 > 0.f) ? 1.f : ((d1 < 0.f) ? -1.f : 0.f);
        float px = ((float)xi + 0.25f * sx) * 2.f;
        float py = ((float)yi + 0.25f * sy) * 2.f;
        if (!(val >= 0.2f)) {
            px = __int_as_float(0x7fc00000);
            py = __int_as_float(0x7fc00000);
        }
        out[bn * 3 + 0] = px;
        out[bn * 3 + 1] = py;
        out[bn * 3 + 2] = val;
    }
}

extern "C" void kernel_launch(void* const* d_in, const int* in_sizes, int n_in,
                              void* d_out, int out_size, void* d_ws, size_t ws_size,
                              hipStream_t stream) {
    const float* crops = (const float*)d_in[0];
    const float* W1 = (const float*)d_in[1];
    const float* b1 = (const float*)d_in[2];
    const float* W2 = (const float*)d_in[3];
    const float* b2 = (const float*)d_in[4];
    float* out = (float*)d_out;
    unsigned long long* peaks = (unsigned long long*)d_ws;

    hipMemsetAsync(d_ws, 0, 128 * NCH * sizeof(unsigned long long), stream);

    dim3 gridB(12, 128);  // 4x3 tiles of 24x32 over 96x96, per image
    conv_peaks_kernel<<<gridB, 256, 0, stream>>>(crops, W1, b1, W2, b2, peaks);
    refine_kernel<<<128 * NCH, 64, 0, stream>>>(crops, W1, b1, W2, peaks, out);
}

// Round 5
// 246.585 us; speedup vs baseline: 1.1384x; 1.1384x over previous
//
#include <hip/hip_runtime.h>

// FindInstancePeaks: fused conv backbone + global peak finding.
// crops (128,192,192,1) f32 -> conv1 3x3 s2 SAME (1->32) + relu
//                          -> conv2 3x3 s1 SAME (32->17) = cms (128,96,96,17)
// -> per (b,n): argmax over 96x96, quarter-pixel sign refine, *2, NaN<0.2.
//
// R13: R12's software pipeline spilled catastrophically (WRITE_SIZE 392 MB:
// acc[51]+hr1[15] live across a barrier PLUS an inlined 2-channel conv1 in
// the same region > the (256,6) ~85-reg cap). Same overlap idea, zero extra
// register cost: LDS double-buffer instead of register-carried state.
//  - CG=1 (32 groups), s_h[2][34*28] (7.6 KB; LDS total 22.2 KB, 6 blk/CU).
//  - per group: barrier; conv1(g+1)->buf[(g+1)&1]  ||  conv2(g)<-buf[g&1].
//    Disjoint buffers -> 1 barrier/group; every region has 459 independent
//    FMAs covering conv1's LDS latency. Only acc lives across barriers.
//  - scalar fmaf (R11/R12: packed fp32 is half-rate; 157.3 TF == scalar
//    issue rate). Accumulation order c=g asc, k asc, q asc == R10 ->
//    bit-exact output (absmax 0.0).

#define NCH 17
#define C1 32
#define TW 24           // tile width
#define TH 32           // tile height
#define HT_W 26         // h cols needed (TW+2)
#define HT_H 34         // h rows needed (TH+2)
#define HSTR 28         // s_h col stride (conv2 read pattern = exact 2-way/bank, free)
#define IN_W 53         // input patch cols: 2*HT_W+1
#define IN_H 69         // input patch rows: 2*HT_H+1
#define NG 32           // groups of 1 conv1 channel
#define NHPX (HT_H * HT_W)   // 884 h-pixels per block
#define SH_PLANE (HT_H * HSTR)

__device__ __forceinline__ unsigned long long pack_key(float v, unsigned flat) {
    unsigned ub = __float_as_uint(v);
    ub = (ub & 0x80000000u) ? ~ub : (ub | 0x80000000u);   // monotone float->uint
    return ((unsigned long long)ub << 32) | (unsigned)(~flat); // ~flat: ties -> lowest idx
}

// conv1 + relu for one channel c into dst plane.
// Weights/bias uniform -> s_loads. Validity via *{0,1}. Live set: w1[9]+in9[9].
__device__ __forceinline__ void conv1_ch(
    const float* __restrict__ W1g, const float* __restrict__ b1g,
    const float* s_in, float* dst, int c, int t, int ty0, int tx0) {
    const float bias = b1g[c];
    float w1[9];
#pragma unroll
    for (int q = 0; q < 9; ++q) w1[q] = W1g[q * C1 + c];
#pragma unroll
    for (int i = 0; i < 4; ++i) {
        int p = t + i * 256;
        if (i < 3 || p < NHPX) {
            int r = p / HT_W, cc = p - r * HT_W;
            int hy = ty0 - 1 + r, hx = tx0 - 1 + cc;
            float vf = (hy >= 0 && hy < 96 && hx >= 0 && hx < 96) ? 1.f : 0.f;
            const float* ip = s_in + 2 * r * IN_W + 2 * cc;
            float a = bias;
#pragma unroll
            for (int qy = 0; qy < 3; ++qy)
#pragma unroll
                for (int qx = 0; qx < 3; ++qx)
                    a = fmaf(ip[qy * IN_W + qx], w1[qy * 3 + qx], a);
            dst[r * HSTR + cc] = fmaxf(a, 0.f) * vf;
        }
    }
}

__global__ __launch_bounds__(256, 6) void conv_peaks_kernel(
    const float* __restrict__ crops, const float* __restrict__ W1g,
    const float* __restrict__ b1g, const float* __restrict__ W2g,
    const float* __restrict__ b2g, unsigned long long* __restrict__ peaks) {
    __shared__ __align__(16) float s_in[IN_H * IN_W];        // 14628 B
    __shared__ __align__(16) float s_h[2][SH_PLANE];         // 7616 B

    const int t = threadIdx.x;
    const int b = blockIdx.y;
    const int ty0 = (blockIdx.x >> 2) * TH;   // 0,32,64
    const int tx0 = (blockIdx.x & 3) * TW;    // 0,24,48,72
    const int iy0 = 2 * ty0 - 2;
    const int ix0 = 2 * tx0 - 2;
    const float* cb = crops + b * 192 * 192;

    // --- stage input patch (zero-padded at image borders) ---
    for (int p = t; p < IN_H * IN_W; p += 256) {
        int r = p / IN_W, cc = p - r * IN_W;
        int iy = iy0 + r, ix = ix0 + cc;
        float v = 0.f;
        if (iy >= 0 && ix >= 0 && iy < 192 && ix < 192) v = cb[iy * 192 + ix];
        s_in[p] = v;
    }
    __syncthreads();
    conv1_ch(W1g, b1g, s_in, s_h[0], 0, t, ty0, tx0);   // prologue: channel 0

    // thread -> 3 contiguous pixels: row ly, cols lx0..lx0+2
    const int ly = t >> 3;            // 0..31
    const int lx0 = (t & 7) * 3;      // 0,3,...,21
    float acc[NCH][3];
#pragma unroll
    for (int n = 0; n < NCH; ++n)
#pragma unroll
        for (int p = 0; p < 3; ++p) acc[n][p] = 0.f;

#pragma unroll 1
    for (int g = 0; g < NG; ++g) {
        __syncthreads();   // conv1(g) writes visible; conv2(g-1) reads done

        // produce next channel into the other buffer (no hazard with conv2(g))
        if (g < NG - 1)
            conv1_ch(W1g, b1g, s_in, s_h[(g + 1) & 1], g + 1, t, ty0, tx0);

        // conv2 partial for channel c = g from buf[g&1]:
        // 15 ds_read_b32 (exact 2 lanes/bank -> conflict-free), then
        // 9 taps x 3 px x 17 channels register FMAs (weights via s_load).
        {
            const float* hp = s_h[g & 1] + ly * HSTR + lx0;
            float hr[3][5];
#pragma unroll
            for (int ky = 0; ky < 3; ++ky)
#pragma unroll
                for (int j = 0; j < 5; ++j) hr[ky][j] = hp[ky * HSTR + j];
#pragma unroll
            for (int k = 0; k < 9; ++k) {
                const int ky = k / 3, kx = k - ky * 3;
                const float* wb = W2g + (k * C1 + g) * NCH;  // uniform -> s_load
                float w[NCH];
#pragma unroll
                for (int n = 0; n < NCH; ++n) w[n] = wb[n];
#pragma unroll
                for (int p = 0; p < 3; ++p) {
                    const float h = hr[ky][kx + p];
#pragma unroll
                    for (int n = 0; n < NCH; ++n)
                        acc[n][p] = fmaf(h, w[n], acc[n][p]);
                }
            }
        }
    }

    // --- per-channel argmax: in-thread max over 3 px, then wave reduce ---
    const int yg = ty0 + ly, xg = tx0 + lx0;
    const int lane = t & 63;
#pragma unroll
    for (int n = 0; n < NCH; ++n) {
        const float bb = b2g[n];
        unsigned long long pk = pack_key(acc[n][0] + bb, (unsigned)(yg * 96 + xg));
#pragma unroll
        for (int p = 1; p < 3; ++p) {
            unsigned long long o = pack_key(acc[n][p] + bb, (unsigned)(yg * 96 + xg + p));
            if (o > pk) pk = o;
        }
#pragma unroll
        for (int off = 32; off; off >>= 1) {
            unsigned long long o = __shfl_down(pk, off, 64);
            if (o > pk) pk = o;
        }
        if (lane == 0) atomicMax(&peaks[b * NCH + n], pk);
    }
}

// One 64-lane wave per (b,n): decode peak, recompute 4 clipped neighbor cms
// values (b2 cancels in the sign differences), emit (x,y,val).
__global__ __launch_bounds__(64) void refine_kernel(
    const float* __restrict__ crops, const float* __restrict__ W1g,
    const float* __restrict__ b1g, const float* __restrict__ W2g,
    const unsigned long long* __restrict__ peaks, float* __restrict__ out) {
    const int bn = blockIdx.x;          // 0..128*17-1
    const int b = bn / NCH, n = bn % NCH;
    const int lane = threadIdx.x;

    unsigned long long pk = peaks[bn];
    unsigned key = (unsigned)(pk >> 32);
    unsigned fbits = (key & 0x80000000u) ? (key ^ 0x80000000u) : ~key;
    float val = __uint_as_float(fbits);
    int flat = (int)(~(unsigned)(pk & 0xffffffffu));
    int yi = flat / 96, xi = flat - yi * 96;

    // neighbor j: 0:(yi,xi+1) 1:(yi,xi-1) 2:(yi+1,xi) 3:(yi-1,xi), clipped
    const int j = lane >> 4;
    int yy = yi + ((j == 2) ? 1 : 0) - ((j == 3) ? 1 : 0);
    int xx = xi + ((j == 0) ? 1 : 0) - ((j == 1) ? 1 : 0);
    yy = min(max(yy, 0), 95);
    xx = min(max(xx, 0), 95);

    // hoist 7x7 crops patch: rows 2yy-2..2yy+4, cols 2xx-2..2xx+4
    const float* cb = crops + b * 192 * 192;
    float pat[7][7];
#pragma unroll
    for (int r = 0; r < 7; ++r) {
        int iy = 2 * yy - 2 + r;
#pragma unroll
        for (int s = 0; s < 7; ++s) {
            int ix = 2 * xx - 2 + s;
            pat[r][s] = (iy >= 0 && iy < 192 && ix >= 0 && ix < 192)
                            ? cb[iy * 192 + ix] : 0.f;
        }
    }

    float part = 0.f;
#pragma unroll
    for (int ci = 0; ci < 2; ++ci) {
        const int c = (lane & 15) + ci * 16;
        const float bias = b1g[c];
        float w1[9];
#pragma unroll
        for (int q = 0; q < 9; ++q) w1[q] = W1g[q * C1 + c];
#pragma unroll
        for (int dy = 0; dy < 3; ++dy) {
#pragma unroll
            for (int dx = 0; dx < 3; ++dx) {
                int hy = yy - 1 + dy, hx = xx - 1 + dx;
                if (hy >= 0 && hy < 96 && hx >= 0 && hx < 96) {
                    float a = bias;
#pragma unroll
                    for (int qy = 0; qy < 3; ++qy)
#pragma unroll
                        for (int qx = 0; qx < 3; ++qx)
                            a = fmaf(pat[2 * dy + qy][2 * dx + qx],
                                     w1[qy * 3 + qx], a);
                    float hval = fmaxf(a, 0.f);
                    part = fmaf(hval, W2g[((dy * 3 + dx) * C1 + c) * NCH + n], part);
                }
            }
        }
    }
    // sum the 16 lanes of each neighbor group
    for (int off = 8; off; off >>= 1) part += __shfl_down(part, off, 16);
    float g0 = __shfl(part, 0, 64);
    float g1 = __shfl(part, 16, 64);
    float g2 = __shfl(part, 32, 64);
    float g3 = __shfl(part, 48, 64);

    if (lane == 0) {
        float d0 = g0 - g1, d1 = g2 - g3;
        float sx = (d0 > 0.f) ? 1.f : ((d0 < 0.f) ? -1.f : 0.f);
        float sy = (d1 > 0.f) ? 1.f : ((d1 < 0.f) ? -1.f : 0.f);
        float px = ((float)xi + 0.25f * sx) * 2.f;
        float py = ((float)yi + 0.25f * sy) * 2.f;
        if (!(val >= 0.2f)) {
            px = __int_as_float(0x7fc00000);
            py = __int_as_float(0x7fc00000);
        }
        out[bn * 3 + 0] = px;
        out[bn * 3 + 1] = py;
        out[bn * 3 + 2] = val;
    }
}

extern "C" void kernel_launch(void* const* d_in, const int* in_sizes, int n_in,
                              void* d_out, int out_size, void* d_ws, size_t ws_size,
                              hipStream_t stream) {
    const float* crops = (const float*)d_in[0];
    const float* W1 = (const float*)d_in[1];
    const float* b1 = (const float*)d_in[2];
    const float* W2 = (const float*)d_in[3];
    const float* b2 = (const float*)d_in[4];
    float* out = (float*)d_out;
    unsigned long long* peaks = (unsigned long long*)d_ws;

    hipMemsetAsync(d_ws, 0, 128 * NCH * sizeof(unsigned long long), stream);

    dim3 gridB(12, 128);  // 4x3 tiles of 24x32 over 96x96, per image
    conv_peaks_kernel<<<gridB, 256, 0, stream>>>(crops, W1, b1, W2, b2, peaks);
    refine_kernel<<<128 * NCH, 64, 0, stream>>>(crops, W1, b1, W2, peaks, out);
}

// Round 6
// 244.659 us; speedup vs baseline: 1.1474x; 1.0079x over previous
//
#include <hip/hip_runtime.h>

// FindInstancePeaks: fused conv backbone + global peak finding.
// crops (128,192,192,1) f32 -> conv1 3x3 s2 SAME (1->32) + relu
//                          -> conv2 3x3 s1 SAME (32->17) = cms (128,96,96,17)
// -> per (b,n): argmax over 96x96, quarter-pixel sign refine, *2, NaN<0.2.
//
// R14: R12/R13 proved 51 persistent accumulators + overlap working set
// cannot fit the ~84-reg cap (spills every time). Halve the accumulator
// footprint by CHANNEL-SPLIT instead of shrinking pixels/thread:
//  - 512-thread blocks; waves 0-3 (t<256) accumulate ch 0-8, waves 4-7
//    accumulate ch 8-16 (ch 8 duplicated -> both halves 9 ch, balanced;
//    duplicate atomicMax of identical keys is idempotent). acc: 51->27.
//  - thread t and t+256 own the SAME 3 pixels (tt = t&255 geometry).
//  - weight/bias/peaks bases wave-uniform via readfirstlane(half*8) ->
//    still s_loads.
//  - keep R13's LDS double-buffer overlap: one barrier per group;
//    conv1(g+1)->buf[(g+1)&1] || conv2(g)<-buf[g&1]. Now it fits:
//    27 acc + 15 hr + 18 conv1 + temps ~ 72 <= 84 @ (512,6) [3 blk/CU,
//    24 waves/CU].
//  - accumulation order per output unchanged (c=g asc, k asc, q asc) ->
//    bit-exact (absmax 0.0).

#define NCH 17
#define C1 32
#define TW 24           // tile width
#define TH 32           // tile height
#define HT_W 26         // h cols needed (TW+2)
#define HT_H 34         // h rows needed (TH+2)
#define HSTR 28         // s_h col stride
#define IN_W 53         // input patch cols: 2*HT_W+1
#define IN_H 69         // input patch rows: 2*HT_H+1
#define NG 32           // groups of 1 conv1 channel
#define NCHH 9          // channels per half (ch8 shared)
#define NHPX (HT_H * HT_W)   // 884 h-pixels per block
#define SH_PLANE (HT_H * HSTR)

__device__ __forceinline__ unsigned long long pack_key(float v, unsigned flat) {
    unsigned ub = __float_as_uint(v);
    ub = (ub & 0x80000000u) ? ~ub : (ub | 0x80000000u);   // monotone float->uint
    return ((unsigned long long)ub << 32) | (unsigned)(~flat); // ~flat: ties -> lowest idx
}

// conv1 + relu for one channel c into dst plane (512 threads -> 2 iters).
// Weights/bias uniform -> s_loads. Validity via *{0,1}.
__device__ __forceinline__ void conv1_ch(
    const float* __restrict__ W1g, const float* __restrict__ b1g,
    const float* s_in, float* dst, int c, int t, int ty0, int tx0) {
    const float bias = b1g[c];
    float w1[9];
#pragma unroll
    for (int q = 0; q < 9; ++q) w1[q] = W1g[q * C1 + c];
#pragma unroll
    for (int i = 0; i < 2; ++i) {
        int p = t + i * 512;
        if (i == 0 || p < NHPX) {
            int r = p / HT_W, cc = p - r * HT_W;
            int hy = ty0 - 1 + r, hx = tx0 - 1 + cc;
            float vf = (hy >= 0 && hy < 96 && hx >= 0 && hx < 96) ? 1.f : 0.f;
            const float* ip = s_in + 2 * r * IN_W + 2 * cc;
            float a = bias;
#pragma unroll
            for (int qy = 0; qy < 3; ++qy)
#pragma unroll
                for (int qx = 0; qx < 3; ++qx)
                    a = fmaf(ip[qy * IN_W + qx], w1[qy * 3 + qx], a);
            dst[r * HSTR + cc] = fmaxf(a, 0.f) * vf;
        }
    }
}

__global__ __launch_bounds__(512, 6) void conv_peaks_kernel(
    const float* __restrict__ crops, const float* __restrict__ W1g,
    const float* __restrict__ b1g, const float* __restrict__ W2g,
    const float* __restrict__ b2g, unsigned long long* __restrict__ peaks) {
    __shared__ __align__(16) float s_in[IN_H * IN_W];        // 14628 B
    __shared__ __align__(16) float s_h[2][SH_PLANE];         // 7616 B

    const int t = threadIdx.x;
    const int b = blockIdx.y;
    const int ty0 = (blockIdx.x >> 2) * TH;   // 0,32,64
    const int tx0 = (blockIdx.x & 3) * TW;    // 0,24,48,72
    const int iy0 = 2 * ty0 - 2;
    const int ix0 = 2 * tx0 - 2;
    const float* cb = crops + b * 192 * 192;

    // --- stage input patch (zero-padded at image borders) ---
    for (int p = t; p < IN_H * IN_W; p += 512) {
        int r = p / IN_W, cc = p - r * IN_W;
        int iy = iy0 + r, ix = ix0 + cc;
        float v = 0.f;
        if (iy >= 0 && ix >= 0 && iy < 192 && ix < 192) v = cb[iy * 192 + ix];
        s_in[p] = v;
    }
    __syncthreads();
    conv1_ch(W1g, b1g, s_in, s_h[0], 0, t, ty0, tx0);   // prologue: channel 0

    // channel split: waves 0-3 -> ch 0..8, waves 4-7 -> ch 8..16 (wave-uniform)
    const int nb = __builtin_amdgcn_readfirstlane((t >> 8) * 8);
    // thread -> 3 contiguous pixels: row ly, cols lx0..lx0+2 (same for t, t+256)
    const int tt = t & 255;
    const int ly = tt >> 3;           // 0..31
    const int lx0 = (tt & 7) * 3;     // 0,3,...,21
    float acc[NCHH][3];
#pragma unroll
    for (int n = 0; n < NCHH; ++n)
#pragma unroll
        for (int p = 0; p < 3; ++p) acc[n][p] = 0.f;

#pragma unroll 1
    for (int g = 0; g < NG; ++g) {
        __syncthreads();   // conv1(g) writes visible; conv2(g-1) reads done

        // produce next channel into the other buffer (no hazard with conv2(g))
        if (g < NG - 1)
            conv1_ch(W1g, b1g, s_in, s_h[(g + 1) & 1], g + 1, t, ty0, tx0);

        // conv2 partial for channel c = g from buf[g&1]:
        // 15 ds_read_b32 (~2 lanes/bank, free), then 9 taps x 3 px x 9 ch
        // register FMAs; weights via wave-uniform s_load (base nb in SGPR).
        {
            const float* hp = s_h[g & 1] + ly * HSTR + lx0;
            float hr[3][5];
#pragma unroll
            for (int ky = 0; ky < 3; ++ky)
#pragma unroll
                for (int j = 0; j < 5; ++j) hr[ky][j] = hp[ky * HSTR + j];
#pragma unroll
            for (int k = 0; k < 9; ++k) {
                const int ky = k / 3, kx = k - ky * 3;
                const float* wb = W2g + (k * C1 + g) * NCH + nb;  // SGPR base
                float w[NCHH];
#pragma unroll
                for (int n = 0; n < NCHH; ++n) w[n] = wb[n];
#pragma unroll
                for (int p = 0; p < 3; ++p) {
                    const float h = hr[ky][kx + p];
#pragma unroll
                    for (int n = 0; n < NCHH; ++n)
                        acc[n][p] = fmaf(h, w[n], acc[n][p]);
                }
            }
        }
    }

    // --- per-channel argmax: in-thread max over 3 px, then wave reduce ---
    // Each wave covers its half's channels; ch8 done by both halves with
    // identical values -> duplicate atomicMax is harmless.
    const int yg = ty0 + ly, xg = tx0 + lx0;
    const int lane = t & 63;
#pragma unroll
    for (int n = 0; n < NCHH; ++n) {
        const float bb = b2g[nb + n];
        unsigned long long pk = pack_key(acc[n][0] + bb, (unsigned)(yg * 96 + xg));
#pragma unroll
        for (int p = 1; p < 3; ++p) {
            unsigned long long o = pack_key(acc[n][p] + bb, (unsigned)(yg * 96 + xg + p));
            if (o > pk) pk = o;
        }
#pragma unroll
        for (int off = 32; off; off >>= 1) {
            unsigned long long o = __shfl_down(pk, off, 64);
            if (o > pk) pk = o;
        }
        if (lane == 0) atomicMax(&peaks[b * NCH + nb + n], pk);
    }
}

// One 64-lane wave per (b,n): decode peak, recompute 4 clipped neighbor cms
// values (b2 cancels in the sign differences), emit (x,y,val).
__global__ __launch_bounds__(64) void refine_kernel(
    const float* __restrict__ crops, const float* __restrict__ W1g,
    const float* __restrict__ b1g, const float* __restrict__ W2g,
    const unsigned long long* __restrict__ peaks, float* __restrict__ out) {
    const int bn = blockIdx.x;          // 0..128*17-1
    const int b = bn / NCH, n = bn % NCH;
    const int lane = threadIdx.x;

    unsigned long long pk = peaks[bn];
    unsigned key = (unsigned)(pk >> 32);
    unsigned fbits = (key & 0x80000000u) ? (key ^ 0x80000000u) : ~key;
    float val = __uint_as_float(fbits);
    int flat = (int)(~(unsigned)(pk & 0xffffffffu));
    int yi = flat / 96, xi = flat - yi * 96;

    // neighbor j: 0:(yi,xi+1) 1:(yi,xi-1) 2:(yi+1,xi) 3:(yi-1,xi), clipped
    const int j = lane >> 4;
    int yy = yi + ((j == 2) ? 1 : 0) - ((j == 3) ? 1 : 0);
    int xx = xi + ((j == 0) ? 1 : 0) - ((j == 1) ? 1 : 0);
    yy = min(max(yy, 0), 95);
    xx = min(max(xx, 0), 95);

    // hoist 7x7 crops patch: rows 2yy-2..2yy+4, cols 2xx-2..2xx+4
    const float* cb = crops + b * 192 * 192;
    float pat[7][7];
#pragma unroll
    for (int r = 0; r < 7; ++r) {
        int iy = 2 * yy - 2 + r;
#pragma unroll
        for (int s = 0; s < 7; ++s) {
            int ix = 2 * xx - 2 + s;
            pat[r][s] = (iy >= 0 && iy < 192 && ix >= 0 && ix < 192)
                            ? cb[iy * 192 + ix] : 0.f;
        }
    }

    float part = 0.f;
#pragma unroll
    for (int ci = 0; ci < 2; ++ci) {
        const int c = (lane & 15) + ci * 16;
        const float bias = b1g[c];
        float w1[9];
#pragma unroll
        for (int q = 0; q < 9; ++q) w1[q] = W1g[q * C1 + c];
#pragma unroll
        for (int dy = 0; dy < 3; ++dy) {
#pragma unroll
            for (int dx = 0; dx < 3; ++dx) {
                int hy = yy - 1 + dy, hx = xx - 1 + dx;
                if (hy >= 0 && hy < 96 && hx >= 0 && hx < 96) {
                    float a = bias;
#pragma unroll
                    for (int qy = 0; qy < 3; ++qy)
#pragma unroll
                        for (int qx = 0; qx < 3; ++qx)
                            a = fmaf(pat[2 * dy + qy][2 * dx + qx],
                                     w1[qy * 3 + qx], a);
                    float hval = fmaxf(a, 0.f);
                    part = fmaf(hval, W2g[((dy * 3 + dx) * C1 + c) * NCH + n], part);
                }
            }
        }
    }
    // sum the 16 lanes of each neighbor group
    for (int off = 8; off; off >>= 1) part += __shfl_down(part, off, 16);
    float g0 = __shfl(part, 0, 64);
    float g1 = __shfl(part, 16, 64);
    float g2 = __shfl(part, 32, 64);
    float g3 = __shfl(part, 48, 64);

    if (lane == 0) {
        float d0 = g0 - g1, d1 = g2 - g3;
        float sx = (d0 > 0.f) ? 1.f : ((d0 < 0.f) ? -1.f : 0.f);
        float sy = (d1 > 0.f) ? 1.f : ((d1 < 0.f) ? -1.f : 0.f);
        float px = ((float)xi + 0.25f * sx) * 2.f;
        float py = ((float)yi + 0.25f * sy) * 2.f;
        if (!(val >= 0.2f)) {
            px = __int_as_float(0x7fc00000);
            py = __int_as_float(0x7fc00000);
        }
        out[bn * 3 + 0] = px;
        out[bn * 3 + 1] = py;
        out[bn * 3 + 2] = val;
    }
}

extern "C" void kernel_launch(void* const* d_in, const int* in_sizes, int n_in,
                              void* d_out, int out_size, void* d_ws, size_t ws_size,
                              hipStream_t stream) {
    const float* crops = (const float*)d_in[0];
    const float* W1 = (const float*)d_in[1];
    const float* b1 = (const float*)d_in[2];
    const float* W2 = (const float*)d_in[3];
    const float* b2 = (const float*)d_in[4];
    float* out = (float*)d_out;
    unsigned long long* peaks = (unsigned long long*)d_ws;

    hipMemsetAsync(d_ws, 0, 128 * NCH * sizeof(unsigned long long), stream);

    dim3 gridB(12, 128);  // 4x3 tiles of 24x32 over 96x96, per image
    conv_peaks_kernel<<<gridB, 512, 0, stream>>>(crops, W1, b1, W2, b2, peaks);
    refine_kernel<<<128 * NCH, 64, 0, stream>>>(crops, W1, b1, W2, peaks, out);
}

// Round 7
// 227.163 us; speedup vs baseline: 1.2357x; 1.0770x over previous
//
#include <hip/hip_runtime.h>

// FindInstancePeaks: fused conv backbone + global peak finding.
// crops (128,192,192,1) f32 -> conv1 3x3 s2 SAME (1->32) + relu
//                          -> conv2 3x3 s1 SAME (32->17) = cms (128,96,96,17)
// -> per (b,n): argmax over 96x96, quarter-pixel sign refine, *2, NaN<0.2.
//
// R15: R14 was LDS-ISSUE-bound, not VALU-bound: ~50.7k ds_read wave-instrs
// per CU x 5.8 cyc ~ 122us of LDS-pipe occupancy (channel-split duplicated
// conv2 reads; CG=1 re-read in9 per channel). Fix: minimize LDS instrs and
// buy registers with occupancy instead of splits:
//  - CG=8 (4 groups): in9 loaded once per pixel, amortized over 8 conv1
//    channels. conv1 reads/thread 576->144; total 624 (~36us LDS pipe).
//  - __launch_bounds__(256,3): reg cap 170; peak live ~95 -> NO spill risk
//    (the R12/R13/R14 killer). Grid 1536 @ 3 blocks/CU = exactly 2 rounds.
//    Occupancy ~37% by design; 51 independent acc chains provide the ILP.
//  - single s_h buffer (8 planes, 30.5KB; LDS total 45KB -> 3 blocks/CU),
//    2 barriers/group x 4 groups = 8 barriers total.
//  - accumulation order per output unchanged (c asc, k asc, q asc) ->
//    bit-exact (absmax 0.0).

#define NCH 17
#define C1 32
#define TW 24           // tile width
#define TH 32           // tile height
#define HT_W 26         // h cols needed (TW+2)
#define HT_H 34         // h rows needed (TH+2)
#define HSTR 28         // s_h col stride
#define IN_W 53         // input patch cols: 2*HT_W+1
#define IN_H 69         // input patch rows: 2*HT_H+1
#define CG 8            // conv1 channels per group
#define NG 4            // groups
#define NHPX (HT_H * HT_W)   // 884 h-pixels per block
#define SH_PLANE (HT_H * HSTR)

__device__ __forceinline__ unsigned long long pack_key(float v, unsigned flat) {
    unsigned ub = __float_as_uint(v);
    ub = (ub & 0x80000000u) ? ~ub : (ub | 0x80000000u);   // monotone float->uint
    return ((unsigned long long)ub << 32) | (unsigned)(~flat); // ~flat: ties -> lowest idx
}

__global__ __launch_bounds__(256, 3) void conv_peaks_kernel(
    const float* __restrict__ crops, const float* __restrict__ W1g,
    const float* __restrict__ b1g, const float* __restrict__ W2g,
    const float* __restrict__ b2g, unsigned long long* __restrict__ peaks) {
    __shared__ __align__(16) float s_in[IN_H * IN_W];        // 14628 B
    __shared__ __align__(16) float s_h[CG * SH_PLANE];       // 30464 B

    const int t = threadIdx.x;
    const int b = blockIdx.y;
    const int ty0 = (blockIdx.x >> 2) * TH;   // 0,32,64
    const int tx0 = (blockIdx.x & 3) * TW;    // 0,24,48,72
    const int iy0 = 2 * ty0 - 2;
    const int ix0 = 2 * tx0 - 2;
    const float* cb = crops + b * 192 * 192;

    // --- stage input patch (zero-padded at image borders) ---
    for (int p = t; p < IN_H * IN_W; p += 256) {
        int r = p / IN_W, cc = p - r * IN_W;
        int iy = iy0 + r, ix = ix0 + cc;
        float v = 0.f;
        if (iy >= 0 && ix >= 0 && iy < 192 && ix < 192) v = cb[iy * 192 + ix];
        s_in[p] = v;
    }

    // thread -> 3 contiguous pixels: row ly, cols lx0..lx0+2
    const int ly = t >> 3;            // 0..31
    const int lx0 = (t & 7) * 3;      // 0,3,...,21
    float acc[NCH][3];
#pragma unroll
    for (int n = 0; n < NCH; ++n)
#pragma unroll
        for (int p = 0; p < 3; ++p) acc[n][p] = 0.f;

#pragma unroll 1
    for (int g = 0; g < NG; ++g) {
        __syncthreads();   // staging done / prev conv2 reads done

        // conv1 + relu for this group's 8 channels: in9 loaded ONCE per
        // pixel, reused across all 8 channels (this is the LDS-pipe fix).
        // Weights referenced directly (uniform -> s_load, scalar-cached).
#pragma unroll
        for (int i = 0; i < 4; ++i) {
            int p = t + i * 256;
            if (i < 3 || t < NHPX - 768) {
                int r = p / HT_W, cc = p - r * HT_W;
                int hy = ty0 - 1 + r, hx = tx0 - 1 + cc;
                float vf = (hy >= 0 && hy < 96 && hx >= 0 && hx < 96) ? 1.f : 0.f;
                const float* ip = s_in + 2 * r * IN_W + 2 * cc;
                float in9[9];
#pragma unroll
                for (int qy = 0; qy < 3; ++qy)
#pragma unroll
                    for (int qx = 0; qx < 3; ++qx)
                        in9[qy * 3 + qx] = ip[qy * IN_W + qx];
#pragma unroll
                for (int cl = 0; cl < CG; ++cl) {
                    const int c = g * CG + cl;
                    float a = b1g[c];
#pragma unroll
                    for (int q = 0; q < 9; ++q)
                        a = fmaf(in9[q], W1g[q * C1 + c], a);
                    s_h[cl * SH_PLANE + r * HSTR + cc] = fmaxf(a, 0.f) * vf;
                }
            }
        }
        __syncthreads();   // conv1(g) visible

        // conv2 partial: per cl: 15 ds_read_b32, then 9 taps x 3 px x 17 ch
        // register FMAs (weights via uniform s_load). 3672 FMAs per group
        // dominate this region -> LDS latency fully hidden.
#pragma unroll 1
        for (int cl = 0; cl < CG; ++cl) {
            const float* hp = s_h + cl * SH_PLANE + ly * HSTR + lx0;
            float hr[3][5];
#pragma unroll
            for (int ky = 0; ky < 3; ++ky)
#pragma unroll
                for (int j = 0; j < 5; ++j) hr[ky][j] = hp[ky * HSTR + j];
            const int c = g * CG + cl;
#pragma unroll
            for (int k = 0; k < 9; ++k) {
                const int ky = k / 3, kx = k - ky * 3;
                const float* wb = W2g + (k * C1 + c) * NCH;  // uniform -> s_load
                float w[NCH];
#pragma unroll
                for (int n = 0; n < NCH; ++n) w[n] = wb[n];
#pragma unroll
                for (int p = 0; p < 3; ++p) {
                    const float h = hr[ky][kx + p];
#pragma unroll
                    for (int n = 0; n < NCH; ++n)
                        acc[n][p] = fmaf(h, w[n], acc[n][p]);
                }
            }
        }
    }

    // --- per-channel argmax: in-thread max over 3 px, then wave reduce ---
    const int yg = ty0 + ly, xg = tx0 + lx0;
    const int lane = t & 63;
#pragma unroll
    for (int n = 0; n < NCH; ++n) {
        const float bb = b2g[n];
        unsigned long long pk = pack_key(acc[n][0] + bb, (unsigned)(yg * 96 + xg));
#pragma unroll
        for (int p = 1; p < 3; ++p) {
            unsigned long long o = pack_key(acc[n][p] + bb, (unsigned)(yg * 96 + xg + p));
            if (o > pk) pk = o;
        }
#pragma unroll
        for (int off = 32; off; off >>= 1) {
            unsigned long long o = __shfl_down(pk, off, 64);
            if (o > pk) pk = o;
        }
        if (lane == 0) atomicMax(&peaks[b * NCH + n], pk);
    }
}

// One 64-lane wave per (b,n): decode peak, recompute 4 clipped neighbor cms
// values (b2 cancels in the sign differences), emit (x,y,val).
__global__ __launch_bounds__(64) void refine_kernel(
    const float* __restrict__ crops, const float* __restrict__ W1g,
    const float* __restrict__ b1g, const float* __restrict__ W2g,
    const unsigned long long* __restrict__ peaks, float* __restrict__ out) {
    const int bn = blockIdx.x;          // 0..128*17-1
    const int b = bn / NCH, n = bn % NCH;
    const int lane = threadIdx.x;

    unsigned long long pk = peaks[bn];
    unsigned key = (unsigned)(pk >> 32);
    unsigned fbits = (key & 0x80000000u) ? (key ^ 0x80000000u) : ~key;
    float val = __uint_as_float(fbits);
    int flat = (int)(~(unsigned)(pk & 0xffffffffu));
    int yi = flat / 96, xi = flat - yi * 96;

    // neighbor j: 0:(yi,xi+1) 1:(yi,xi-1) 2:(yi+1,xi) 3:(yi-1,xi), clipped
    const int j = lane >> 4;
    int yy = yi + ((j == 2) ? 1 : 0) - ((j == 3) ? 1 : 0);
    int xx = xi + ((j == 0) ? 1 : 0) - ((j == 1) ? 1 : 0);
    yy = min(max(yy, 0), 95);
    xx = min(max(xx, 0), 95);

    // hoist 7x7 crops patch: rows 2yy-2..2yy+4, cols 2xx-2..2xx+4
    const float* cb = crops + b * 192 * 192;
    float pat[7][7];
#pragma unroll
    for (int r = 0; r < 7; ++r) {
        int iy = 2 * yy - 2 + r;
#pragma unroll
        for (int s = 0; s < 7; ++s) {
            int ix = 2 * xx - 2 + s;
            pat[r][s] = (iy >= 0 && iy < 192 && ix >= 0 && ix < 192)
                            ? cb[iy * 192 + ix] : 0.f;
        }
    }

    float part = 0.f;
#pragma unroll
    for (int ci = 0; ci < 2; ++ci) {
        const int c = (lane & 15) + ci * 16;
        const float bias = b1g[c];
        float w1[9];
#pragma unroll
        for (int q = 0; q < 9; ++q) w1[q] = W1g[q * C1 + c];
#pragma unroll
        for (int dy = 0; dy < 3; ++dy) {
#pragma unroll
            for (int dx = 0; dx < 3; ++dx) {
                int hy = yy - 1 + dy, hx = xx - 1 + dx;
                if (hy >= 0 && hy < 96 && hx >= 0 && hx < 96) {
                    float a = bias;
#pragma unroll
                    for (int qy = 0; qy < 3; ++qy)
#pragma unroll
                        for (int qx = 0; qx < 3; ++qx)
                            a = fmaf(pat[2 * dy + qy][2 * dx + qx],
                                     w1[qy * 3 + qx], a);
                    float hval = fmaxf(a, 0.f);
                    part = fmaf(hval, W2g[((dy * 3 + dx) * C1 + c) * NCH + n], part);
                }
            }
        }
    }
    // sum the 16 lanes of each neighbor group
    for (int off = 8; off; off >>= 1) part += __shfl_down(part, off, 16);
    float g0 = __shfl(part, 0, 64);
    float g1 = __shfl(part, 16, 64);
    float g2 = __shfl(part, 32, 64);
    float g3 = __shfl(part, 48, 64);

    if (lane == 0) {
        float d0 = g0 - g1, d1 = g2 - g3;
        float sx = (d0 > 0.f) ? 1.f : ((d0 < 0.f) ? -1.f : 0.f);
        float sy = (d1 > 0.f) ? 1.f : ((d1 < 0.f) ? -1.f : 0.f);
        float px = ((float)xi + 0.25f * sx) * 2.f;
        float py = ((float)yi + 0.25f * sy) * 2.f;
        if (!(val >= 0.2f)) {
            px = __int_as_float(0x7fc00000);
            py = __int_as_float(0x7fc00000);
        }
        out[bn * 3 + 0] = px;
        out[bn * 3 + 1] = py;
        out[bn * 3 + 2] = val;
    }
}

extern "C" void kernel_launch(void* const* d_in, const int* in_sizes, int n_in,
                              void* d_out, int out_size, void* d_ws, size_t ws_size,
                              hipStream_t stream) {
    const float* crops = (const float*)d_in[0];
    const float* W1 = (const float*)d_in[1];
    const float* b1 = (const float*)d_in[2];
    const float* W2 = (const float*)d_in[3];
    const float* b2 = (const float*)d_in[4];
    float* out = (float*)d_out;
    unsigned long long* peaks = (unsigned long long*)d_ws;

    hipMemsetAsync(d_ws, 0, 128 * NCH * sizeof(unsigned long long), stream);

    dim3 gridB(12, 128);  // 4x3 tiles of 24x32 over 96x96, per image
    conv_peaks_kernel<<<gridB, 256, 0, stream>>>(crops, W1, b1, W2, b2, peaks);
    refine_kernel<<<128 * NCH, 64, 0, stream>>>(crops, W1, b1, W2, peaks, out);
}